// Round 1
// baseline (1114.254 us; speedup 1.0000x reference)
//
#include <hip/hip_runtime.h>
#include <hip/hip_bf16.h>

// LSTM cell fused kernel for MI355X.
// gates[b,gc] = sum_k A[b,k] * W[gc,k],  A=[x|hx] (4096x4096), W=[Wx|Wh] (8192x4096)
// f32 accuracy via f16 split: v = hi + lo;  C = hi*hi + hi*lo + lo*hi (3 MFMAs).
// Effective 128x128 GEMM tile = 128 b-rows x (4 gates x 32 h-cols), gate dim in
// the N-fragment index so the LSTM epilogue is per-thread in-register.

typedef _Float16 half8 __attribute__((ext_vector_type(8)));
typedef _Float16 half4 __attribute__((ext_vector_type(4)));
typedef float    f32x4 __attribute__((ext_vector_type(4)));

#define B_DIM   4096
#define H_DIM   2048
#define K_TOT   4096
#define GC_TOT  8192
#define BH_TOT  (B_DIM * H_DIM)   // 8388608

__device__ __forceinline__ void gload_lds16(const void* g, void* l) {
    __builtin_amdgcn_global_load_lds(
        (const __attribute__((address_space(1))) unsigned int*)g,
        (__attribute__((address_space(3))) unsigned int*)l,
        16, 0, 0);
}

__device__ __forceinline__ float fast_sigmoid(float x) {
    return 1.0f / (1.0f + __expf(-x));
}
__device__ __forceinline__ float fast_tanh(float x) {
    // 1 - 2/(e^{2x}+1): saturates correctly at +/-1 without inf/inf.
    float e = __expf(2.0f * x);
    return 1.0f - 2.0f / (e + 1.0f);
}

// ---------------- preconv: split f32 -> f16 hi/lo into packed ws arrays ------
// src is [R][2048] row-major; dst hi/lo are [R][4096] at column offset colOff.
__global__ void split_kernel(const float* __restrict__ src,
                             _Float16* __restrict__ hi, _Float16* __restrict__ lo,
                             int colOff, int n4) {
    int i = blockIdx.x * blockDim.x + threadIdx.x;
    if (i >= n4) return;
    float4 v = ((const float4*)src)[i];
    int idx = i << 2;
    int r = idx >> 11;           // srcCols = 2048
    int c = idx & 2047;
    long d = (long)r * 4096 + colOff + c;
    half4 h4, l4;
    float vv[4] = {v.x, v.y, v.z, v.w};
    #pragma unroll
    for (int j = 0; j < 4; ++j) {
        _Float16 h = (_Float16)vv[j];
        h4[j] = h;
        l4[j] = (_Float16)(vv[j] - (float)h);
    }
    *(half4*)&hi[d] = h4;
    *(half4*)&lo[d] = l4;
}

// ---------------- fused GEMM + LSTM epilogue --------------------------------
// Effective col c in [0,128): gate = (c>>4)&3, h = h0 + (c>>6)*16 + (c&15).
__device__ __forceinline__ int gcof(int c, int h0) {
    return ((c >> 4) & 3) * H_DIM + h0 + (c >> 6) * 16 + (c & 15);
}

template <bool PRECONV>
__global__ __launch_bounds__(256, 2)
void lstm_gemm(const _Float16* __restrict__ Ahi, const _Float16* __restrict__ Alo,
               const _Float16* __restrict__ Whi, const _Float16* __restrict__ Wlo,
               const float* __restrict__ x,  const float* __restrict__ hx,
               const float* __restrict__ Wx, const float* __restrict__ Wh,
               const float* __restrict__ bx, const float* __restrict__ bh,
               const float* __restrict__ cx, float* __restrict__ out) {
    __shared__ _Float16 sAh[128 * 32];
    __shared__ _Float16 sAl[128 * 32];
    __shared__ _Float16 sWh[128 * 32];
    __shared__ _Float16 sWl[128 * 32];

    const int t = threadIdx.x;
    const int w = t >> 6, l = t & 63;
    const int wr = w >> 1, wc = w & 1;
    const int rb = blockIdx.y, cb = blockIdx.x;
    const int h0 = cb * 32;

    f32x4 acc[4][4] = {};

    const int laneRow = l & 15;
    const int laneK8 = (l >> 4) * 8;

    // ---- staging geometry (PRECONV path): per array, wave w stages chunks
    // {2w, 2w+1}; chunk ch covers tile rows [ch*16, ch*16+16), lane l handles
    // row ch*16 + (l>>2), k-bytes (l&3)*16. Linear LDS order == lane*16B. ----
    const int srow = l >> 2;
    const int skc = (l & 3) * 8;
    const int ac0 = 2 * w, ac1 = 2 * w + 1;
    const long ag0 = (long)(rb * 128 + ac0 * 16 + srow) * K_TOT;
    const long ag1 = (long)(rb * 128 + ac1 * 16 + srow) * K_TOT;
    const long wg0 = (long)gcof(ac0 * 16 + srow, h0) * K_TOT;
    const long wg1 = (long)gcof(ac1 * 16 + srow, h0) * K_TOT;

    // ---- reg-stage geometry (fallback path) ----
    const int fr = t >> 1;            // 0..127: tile row / eff col
    const int fkp = (t & 1) * 16;     // 0 or 16
    const long farow = (long)(rb * 128 + fr) * H_DIM;   // source rows are 2048 wide
    const long fwrow = (long)gcof(fr, h0) * H_DIM;

    for (int kt = 0; kt < K_TOT / 32; ++kt) {
        const int k0 = kt * 32;
        if constexpr (PRECONV) {
            const int koff = k0 + skc;
            gload_lds16(Ahi + ag0 + koff, &sAh[ac0 * 512]);
            gload_lds16(Ahi + ag1 + koff, &sAh[ac1 * 512]);
            gload_lds16(Alo + ag0 + koff, &sAl[ac0 * 512]);
            gload_lds16(Alo + ag1 + koff, &sAl[ac1 * 512]);
            gload_lds16(Whi + wg0 + koff, &sWh[ac0 * 512]);
            gload_lds16(Whi + wg1 + koff, &sWh[ac1 * 512]);
            gload_lds16(Wlo + wg0 + koff, &sWl[ac0 * 512]);
            gload_lds16(Wlo + wg1 + koff, &sWl[ac1 * 512]);
        } else {
            const float* as_ = (k0 < H_DIM) ? x : hx;
            const float* ws_ = (k0 < H_DIM) ? Wx : Wh;
            const int kk = k0 & (H_DIM - 1);
            float4 av[4], wv[4];
            #pragma unroll
            for (int j = 0; j < 4; ++j) {
                av[j] = *(const float4*)&as_[farow + kk + fkp + j * 4];
                wv[j] = *(const float4*)&ws_[fwrow + kk + fkp + j * 4];
            }
            #pragma unroll
            for (int j = 0; j < 4; ++j) {
                half4 ah, al, wh, wl;
                float a4[4] = {av[j].x, av[j].y, av[j].z, av[j].w};
                float w4[4] = {wv[j].x, wv[j].y, wv[j].z, wv[j].w};
                #pragma unroll
                for (int jj = 0; jj < 4; ++jj) {
                    _Float16 h = (_Float16)a4[jj];
                    ah[jj] = h; al[jj] = (_Float16)(a4[jj] - (float)h);
                    h = (_Float16)w4[jj];
                    wh[jj] = h; wl[jj] = (_Float16)(w4[jj] - (float)h);
                }
                *(half4*)&sAh[fr * 32 + fkp + j * 4] = ah;
                *(half4*)&sAl[fr * 32 + fkp + j * 4] = al;
                *(half4*)&sWh[fr * 32 + fkp + j * 4] = wh;
                *(half4*)&sWl[fr * 32 + fkp + j * 4] = wl;
            }
        }
        __syncthreads();

        half8 a_h[4], a_l[4], w_h[4], w_l[4];
        #pragma unroll
        for (int m = 0; m < 4; ++m) {
            const int ar = wr * 64 + m * 16 + laneRow;
            a_h[m] = *(const half8*)&sAh[ar * 32 + laneK8];
            a_l[m] = *(const half8*)&sAl[ar * 32 + laneK8];
            const int wcol = wc * 64 + m * 16 + laneRow;
            w_h[m] = *(const half8*)&sWh[wcol * 32 + laneK8];
            w_l[m] = *(const half8*)&sWl[wcol * 32 + laneK8];
        }
        #pragma unroll
        for (int m = 0; m < 4; ++m) {
            #pragma unroll
            for (int n = 0; n < 4; ++n) {
                acc[m][n] = __builtin_amdgcn_mfma_f32_16x16x32_f16(a_h[m], w_h[n], acc[m][n], 0, 0, 0);
                acc[m][n] = __builtin_amdgcn_mfma_f32_16x16x32_f16(a_h[m], w_l[n], acc[m][n], 0, 0, 0);
                acc[m][n] = __builtin_amdgcn_mfma_f32_16x16x32_f16(a_l[m], w_h[n], acc[m][n], 0, 0, 0);
            }
        }
        __syncthreads();
    }

    // ---- fused LSTM epilogue, fully in-register (n-fragment == gate) ----
    const int hcol = h0 + wc * 16 + laneRow;
    float bs[4];
    #pragma unroll
    for (int g = 0; g < 4; ++g) bs[g] = bx[g * H_DIM + hcol] + bh[g * H_DIM + hcol];

    #pragma unroll
    for (int m = 0; m < 4; ++m) {
        #pragma unroll
        for (int r = 0; r < 4; ++r) {
            const int brow = rb * 128 + wr * 64 + m * 16 + (l >> 4) * 4 + r;
            const long base = (long)brow * H_DIM + hcol;
            const float iv = fast_sigmoid(acc[m][0][r] + bs[0]);
            const float fv = fast_sigmoid(acc[m][1][r] + bs[1]);
            const float gv = fast_tanh(acc[m][2][r] + bs[2]);
            const float ov = fast_sigmoid(acc[m][3][r] + bs[3]);
            const float c0 = cx[base];
            const float cyv = fv * c0 + iv * gv;
            const float hyv = ov * fast_tanh(cyv);
            out[base] = hyv;
            out[BH_TOT + base] = cyv;
        }
    }
}

extern "C" void kernel_launch(void* const* d_in, const int* in_sizes, int n_in,
                              void* d_out, int out_size, void* d_ws, size_t ws_size,
                              hipStream_t stream) {
    const float* x  = (const float*)d_in[0];
    const float* hx = (const float*)d_in[1];
    const float* cx = (const float*)d_in[2];
    const float* Wx = (const float*)d_in[3];
    const float* bx = (const float*)d_in[4];
    const float* Wh = (const float*)d_in[5];
    const float* bh = (const float*)d_in[6];
    float* out = (float*)d_out;

    const size_t need = 201326592;  // 192 MiB: A hi/lo (2x32MiB) + W hi/lo (2x64MiB)
    if (ws_size >= need) {
        _Float16* Ahi = (_Float16*)d_ws;
        _Float16* Alo = Ahi + 16777216;
        _Float16* Whi = (_Float16*)((char*)d_ws + 67108864);
        _Float16* Wlo = Whi + 33554432;
        // x -> A[:,0:2048], hx -> A[:,2048:4096]
        split_kernel<<<8192, 256, 0, stream>>>(x,  Ahi, Alo, 0,    2097152);
        split_kernel<<<8192, 256, 0, stream>>>(hx, Ahi, Alo, 2048, 2097152);
        // Wx -> W[:,0:2048], Wh -> W[:,2048:4096]
        split_kernel<<<16384, 256, 0, stream>>>(Wx, Whi, Wlo, 0,    4194304);
        split_kernel<<<16384, 256, 0, stream>>>(Wh, Whi, Wlo, 2048, 4194304);
        lstm_gemm<true><<<dim3(64, 32), 256, 0, stream>>>(
            Ahi, Alo, Whi, Wlo, nullptr, nullptr, nullptr, nullptr, bx, bh, cx, out);
    } else {
        lstm_gemm<false><<<dim3(64, 32), 256, 0, stream>>>(
            nullptr, nullptr, nullptr, nullptr, x, hx, Wx, Wh, bx, bh, cx, out);
    }
}

// Round 2
// 921.358 us; speedup vs baseline: 1.2094x; 1.2094x over previous
//
#include <hip/hip_runtime.h>
#include <hip/hip_bf16.h>

// LSTM cell fused kernel for MI355X — round 2: 256^2 8-phase schedule (T1-T5).
// gates[b,gc] = sum_k A[b,k]*W[gc,k], A=[x|hx] (4096x4096), W=[Wx|Wh] (8192x4096).
// f32 accuracy via f16 split v=hi+lo, C = hi*hi + hi*lo + lo*hi (3 MFMAs).
// hi/lo packed K-interleaved: X2[r][64t + 0..31] = hi of k-block t,
//                             X2[r][64t + 32..63] = lo of k-block t.
// => GEMM over K2=8192 with BK2=64 == the m201 256^2 template geometry.

typedef _Float16 half8 __attribute__((ext_vector_type(8)));
typedef _Float16 half4 __attribute__((ext_vector_type(4)));
typedef float    f32x4 __attribute__((ext_vector_type(4)));

#define H_DIM  2048
#define BH_TOT 8388608
#define NT     128            // 8192 / 64 K2-tiles
#define W2_OFF 67108864u      // A2 = 64 MiB, W2 follows

__device__ __forceinline__ void gload_lds16(const void* g, void* l) {
    __builtin_amdgcn_global_load_lds(
        (const __attribute__((address_space(1))) unsigned int*)g,
        (__attribute__((address_space(3))) unsigned int*)l,
        16, 0, 0);
}

__device__ __forceinline__ void barrier_all() {
    __builtin_amdgcn_sched_barrier(0);
    __builtin_amdgcn_s_barrier();
    __builtin_amdgcn_sched_barrier(0);
}

__device__ __forceinline__ float fast_sigmoid(float x) {
    return 1.0f / (1.0f + __expf(-x));
}
__device__ __forceinline__ float fast_tanh(float x) {
    float e = __expf(2.0f * x);
    return 1.0f - 2.0f / (e + 1.0f);
}

// ---------------- split f32 -> f16 hi/lo, K-interleaved --------------------
// src [R][2048] row-major; dst rows are 8192 f16 wide; k = colOff + c.
__global__ void split_kernel(const float* __restrict__ src,
                             _Float16* __restrict__ dst, int colOff, int n4) {
    const int stride = gridDim.x * blockDim.x;
    for (int i = blockIdx.x * blockDim.x + threadIdx.x; i < n4; i += stride) {
        float4 v = ((const float4*)src)[i];
        int idx = i << 2;
        int r = idx >> 11;
        int c = idx & 2047;
        int k = colOff + c;
        long d = (long)r * 8192 + (k >> 5) * 64 + (k & 31);
        half4 h4, l4;
        float vv[4] = {v.x, v.y, v.z, v.w};
        #pragma unroll
        for (int j = 0; j < 4; ++j) {
            _Float16 h = (_Float16)vv[j];
            h4[j] = h;
            l4[j] = (_Float16)(vv[j] - (float)h);
        }
        *(half4*)&dst[d] = h4;
        *(half4*)&dst[d + 32] = l4;
    }
}

// ---------------- 8-phase fused GEMM + LSTM epilogue ------------------------
// Block: 256 b-rows x 256 eff-cols (= 4 gates x 64 h-cols). 8 waves (2M x 4N).
// eff col e in [0,256): wc=e>>6, gate=(e>>4)&3, hr=e&15
//   -> gc = gate*2048 + cb*64 + wc*16 + hr. Wave wc frag n == gate n.
#define MFMA3(AM, WN, ACC)                                                   \
    ACC = __builtin_amdgcn_mfma_f32_16x16x32_f16(AM[0], WN[0], ACC, 0, 0, 0); \
    ACC = __builtin_amdgcn_mfma_f32_16x16x32_f16(AM[0], WN[1], ACC, 0, 0, 0); \
    ACC = __builtin_amdgcn_mfma_f32_16x16x32_f16(AM[1], WN[0], ACC, 0, 0, 0);

__global__ __launch_bounds__(512, 2)
void lstm8p(const char* __restrict__ wsbase,
            const float* __restrict__ bx, const float* __restrict__ bh,
            const float* __restrict__ cx, float* __restrict__ out) {
    __shared__ _Float16 sm[2][2][256 * 64];   // [dbuf][A=0/W=1], 128 KiB total

    const int t = threadIdx.x;
    const int wid = t >> 6;
    const int l = t & 63;
    const int wr = wid >> 2;     // 0..1
    const int wc = wid & 3;      // 0..3

    // T1: bijective XCD swizzle (512 % 8 == 0), cb fast-varying per chunk.
    const int bid = blockIdx.x;
    const int swz = (bid & 7) * 64 + (bid >> 3);
    const int cb = swz & 31;     // 64 h-cols
    const int rb = swz >> 5;     // 256 b-rows

    // ---- staging geometry: per K-tile, 4 A-gloads + 4 W-gloads per wave.
    // gload g covers rows [g*64+wid*8, +8), lane l -> row +(l>>3), 16B slot
    // (l&7). T2 pre-swizzle on the GLOBAL side: slot s holds global chunk
    // s ^ (row&7); row&7 == l>>3 here.
    const int lr = l >> 3;
    const int ks = ((l & 7) ^ lr) * 8;       // f16 elements within the 64-k row
    unsigned offA[4], offW[4];
    #pragma unroll
    for (int g = 0; g < 4; ++g) {
        const int rowA = rb * 256 + g * 64 + wid * 8 + lr;
        offA[g] = (unsigned)rowA * 16384u + (unsigned)ks * 2u;
        const int e = g * 64 + wid * 8 + lr;
        const int gc = ((e >> 4) & 3) * H_DIM + cb * 64 + (e >> 6) * 16 + (e & 15);
        offW[g] = W2_OFF + (unsigned)gc * 16384u + (unsigned)ks * 2u;
    }
    const int ldsrow = wid * 8;

    auto STAGE = [&](int kt, int db) {
        const unsigned kb = (unsigned)kt * 128u;
        #pragma unroll
        for (int g = 0; g < 4; ++g)
            gload_lds16(wsbase + offA[g] + kb, (_Float16*)&sm[db][0][(g * 64 + ldsrow) * 64]);
        #pragma unroll
        for (int g = 0; g < 4; ++g)
            gload_lds16(wsbase + offW[g] + kb, (_Float16*)&sm[db][1][(g * 64 + ldsrow) * 64]);
    };

    // ---- fragment-read lane offsets (bytes in [256][64] tile, T2 swizzled).
    // row = base16 + (l&15); global 16B-chunk (tm*4 + (l>>4)) lives at LDS
    // chunk ^ (row&7); row&7 == l&7.
    int laneF[2];
    #pragma unroll
    for (int tm = 0; tm < 2; ++tm)
        laneF[tm] = (l & 15) * 128 + (((tm * 4 + (l >> 4)) ^ (l & 7)) << 4);

    auto LDA = [&](int db, int m, int tm) -> half8 {
        const char* p = (const char*)&sm[db][0][0] + (wr * 128 + m * 16) * 128 + laneF[tm];
        return *(const half8*)p;
    };
    auto LDW = [&](int db, int n, int tm) -> half8 {
        const char* p = (const char*)&sm[db][1][0] + (wc * 64 + n * 16) * 128 + laneF[tm];
        return *(const half8*)p;
    };

    f32x4 acc[8][4];
    #pragma unroll
    for (int m = 0; m < 8; ++m)
        #pragma unroll
        for (int n = 0; n < 4; ++n) acc[m][n] = (f32x4){0.f, 0.f, 0.f, 0.f};

    // ---- prologue: stage kt0 -> buf0, kt1 -> buf1; wait kt0 (8 newest = kt1).
    STAGE(0, 0);
    STAGE(1, 1);
    asm volatile("s_waitcnt vmcnt(8)" ::: "memory");
    barrier_all();

    half8 a[4][2], w[4][2];
    for (int kt = 0; kt < NT; ++kt) {
        const int cur = kt & 1;
        // ---- phase 0: read A[0-3] hi/lo + W[0-1] hi/lo; MFMA quad (0,0) ----
        #pragma unroll
        for (int m = 0; m < 4; ++m) { a[m][0] = LDA(cur, m, 0); a[m][1] = LDA(cur, m, 1); }
        #pragma unroll
        for (int n = 0; n < 2; ++n) { w[n][0] = LDW(cur, n, 0); w[n][1] = LDW(cur, n, 1); }
        barrier_all();
        __builtin_amdgcn_s_setprio(1);
        #pragma unroll
        for (int m = 0; m < 4; ++m) {
            MFMA3(a[m], w[0], acc[m][0]);
            MFMA3(a[m], w[1], acc[m][1]);
        }
        __builtin_amdgcn_s_setprio(0);
        barrier_all();
        // ---- phase 1: read W[2-3]; MFMA quad (0,1) ----
        #pragma unroll
        for (int n = 2; n < 4; ++n) { w[n][0] = LDW(cur, n, 0); w[n][1] = LDW(cur, n, 1); }
        barrier_all();
        __builtin_amdgcn_s_setprio(1);
        #pragma unroll
        for (int m = 0; m < 4; ++m) {
            MFMA3(a[m], w[2], acc[m][2]);
            MFMA3(a[m], w[3], acc[m][3]);
        }
        __builtin_amdgcn_s_setprio(0);
        barrier_all();
        // ---- phase 2: read A[4-7]; MFMA quad (1,0) ----
        #pragma unroll
        for (int m = 0; m < 4; ++m) { a[m][0] = LDA(cur, m + 4, 0); a[m][1] = LDA(cur, m + 4, 1); }
        barrier_all();
        __builtin_amdgcn_s_setprio(1);
        #pragma unroll
        for (int m = 0; m < 4; ++m) {
            MFMA3(a[m], w[0], acc[m + 4][0]);
            MFMA3(a[m], w[1], acc[m + 4][1]);
        }
        __builtin_amdgcn_s_setprio(0);
        barrier_all();
        // ---- phase 3: stage kt+2 into buf[cur] (all reads of it are done);
        //      MFMA quad (1,1); counted vmcnt at the tile boundary ----
        if (kt + 2 < NT) STAGE(kt + 2, cur);
        barrier_all();
        __builtin_amdgcn_s_setprio(1);
        #pragma unroll
        for (int m = 0; m < 4; ++m) {
            MFMA3(a[m], w[2], acc[m + 4][2]);
            MFMA3(a[m], w[3], acc[m + 4][3]);
        }
        __builtin_amdgcn_s_setprio(0);
        if (kt < NT - 2) {
            asm volatile("s_waitcnt vmcnt(8)" ::: "memory");   // kt+1 done; kt+2 in flight
        } else if (kt == NT - 2) {
            asm volatile("s_waitcnt vmcnt(0)" ::: "memory");   // drain for last tile
        }
        barrier_all();
    }

    // ---- fused LSTM epilogue, fully in-register (frag n == gate n) ----
    const int hcol = cb * 64 + wc * 16 + (l & 15);
    float bs[4];
    #pragma unroll
    for (int g = 0; g < 4; ++g) bs[g] = bx[g * H_DIM + hcol] + bh[g * H_DIM + hcol];
    const int row0 = rb * 256 + wr * 128 + (l >> 4) * 4;
    #pragma unroll
    for (int m = 0; m < 8; ++m) {
        #pragma unroll
        for (int r = 0; r < 4; ++r) {
            const long base = (long)(row0 + m * 16 + r) * H_DIM + hcol;
            const float iv = fast_sigmoid(acc[m][0][r] + bs[0]);
            const float fv = fast_sigmoid(acc[m][1][r] + bs[1]);
            const float gv = fast_tanh(acc[m][2][r] + bs[2]);
            const float ov = fast_sigmoid(acc[m][3][r] + bs[3]);
            const float c0 = cx[base];
            const float cyv = fv * c0 + iv * gv;
            const float hyv = ov * fast_tanh(cyv);
            out[base] = hyv;
            out[BH_TOT + base] = cyv;
        }
    }
}

extern "C" void kernel_launch(void* const* d_in, const int* in_sizes, int n_in,
                              void* d_out, int out_size, void* d_ws, size_t ws_size,
                              hipStream_t stream) {
    (void)in_sizes; (void)n_in; (void)out_size; (void)ws_size;
    const float* x  = (const float*)d_in[0];
    const float* hx = (const float*)d_in[1];
    const float* cx = (const float*)d_in[2];
    const float* Wx = (const float*)d_in[3];
    const float* bx = (const float*)d_in[4];
    const float* Wh = (const float*)d_in[5];
    const float* bh = (const float*)d_in[6];
    float* out = (float*)d_out;

    _Float16* A2 = (_Float16*)d_ws;                         // 4096 x 8192 f16
    _Float16* W2 = (_Float16*)((char*)d_ws + W2_OFF);       // 8192 x 8192 f16

    split_kernel<<<2048, 256, 0, stream>>>(x,  A2, 0,    2097152);
    split_kernel<<<2048, 256, 0, stream>>>(hx, A2, 2048, 2097152);
    split_kernel<<<2048, 256, 0, stream>>>(Wx, W2, 0,    4194304);
    split_kernel<<<2048, 256, 0, stream>>>(Wh, W2, 2048, 4194304);

    lstm8p<<<512, 512, 0, stream>>>((const char*)d_ws, bx, bh, cx, out);
}

// Round 5
// 828.841 us; speedup vs baseline: 1.3444x; 1.1116x over previous
//
#include <hip/hip_runtime.h>
#include <hip/hip_bf16.h>

// LSTM cell fused kernel for MI355X — round 3: schedule cleanup of the round-2
// 256^2 8-phase structure. gates[b,gc] = sum_k A[b,k]*W[gc,k],
// A=[x|hx] (4096x4096), W=[Wx|Wh] (8192x4096), f16 split v=hi+lo,
// C = hi*hi + hi*lo + lo*hi (3 MFMAs per 32-k block).
// hi/lo packed K-interleaved: X2[r][64t+0..31]=hi, X2[r][64t+32..63]=lo.
// R3 changes vs R2: static dbuf (x2 unroll), plain s_barrier (no sched_barrier),
// 7 barriers/tile, staging spread W@p2/A@p3, W-columns partitioned per XCD,
// single fused split kernel.

typedef _Float16 half8 __attribute__((ext_vector_type(8)));
typedef _Float16 half4 __attribute__((ext_vector_type(4)));
typedef float    f32x4 __attribute__((ext_vector_type(4)));

#define H_DIM  2048
#define BH_TOT 8388608
#define NT     128            // 8192 / 64 K2-tiles
#define W2_OFF 67108864u      // A2 = 64 MiB, W2 follows

__device__ __forceinline__ void gload_lds16(const void* g, void* l) {
    __builtin_amdgcn_global_load_lds(
        (const __attribute__((address_space(1))) unsigned int*)g,
        (__attribute__((address_space(3))) unsigned int*)l,
        16, 0, 0);
}

__device__ __forceinline__ float fast_sigmoid(float x) {
    return 1.0f / (1.0f + __expf(-x));
}
__device__ __forceinline__ float fast_tanh(float x) {
    float e = __expf(2.0f * x);
    return 1.0f - 2.0f / (e + 1.0f);
}

// ---------------- fused split: f32 -> f16 hi/lo, K-interleaved --------------
// Regions (float4 index space): [0,2M) x->A2, [2M,4M) hx->A2(+2048),
// [4M,8M) Wx->W2, [8M,12M) Wh->W2(+2048). Src rows are 2048 f32 wide.
__global__ void split_all(const float* __restrict__ x, const float* __restrict__ hx,
                          const float* __restrict__ Wx, const float* __restrict__ Wh,
                          _Float16* __restrict__ A2, _Float16* __restrict__ W2) {
    const int stride = gridDim.x * blockDim.x;
    for (int i = blockIdx.x * blockDim.x + threadIdx.x; i < 12582912; i += stride) {
        const float* src; _Float16* dst; int ri, colOff;
        if (i < 4194304) {
            dst = A2;
            if (i < 2097152) { src = x;  ri = i;           colOff = 0; }
            else             { src = hx; ri = i - 2097152; colOff = 2048; }
        } else {
            dst = W2;
            int j = i - 4194304;
            if (j < 4194304) { src = Wx; ri = j;           colOff = 0; }
            else             { src = Wh; ri = j - 4194304; colOff = 2048; }
        }
        float4 v = ((const float4*)src)[ri];
        int idx = ri << 2;
        int r = idx >> 11;
        int k = colOff + (idx & 2047);
        long d = (long)r * 8192 + (k >> 5) * 64 + (k & 31);
        half4 h4, l4;
        float vv[4] = {v.x, v.y, v.z, v.w};
        #pragma unroll
        for (int j = 0; j < 4; ++j) {
            _Float16 h = (_Float16)vv[j];
            h4[j] = h;
            l4[j] = (_Float16)(vv[j] - (float)h);
        }
        *(half4*)&dst[d] = h4;
        *(half4*)&dst[d + 32] = l4;
    }
}

// ---------------- 8-phase fused GEMM + LSTM epilogue ------------------------
// Block: 256 b-rows x 256 eff-cols (4 gates x 64 h-cols). 8 waves (2M x 4N).
// eff col e: gate=(e>>4)&3, gc = gate*2048 + cb*64 + (e>>6)*16 + (e&15).
#define MFMA3(AM, WN, ACC)                                                    \
    ACC = __builtin_amdgcn_mfma_f32_16x16x32_f16(AM[0], WN[0], ACC, 0, 0, 0); \
    ACC = __builtin_amdgcn_mfma_f32_16x16x32_f16(AM[0], WN[1], ACC, 0, 0, 0); \
    ACC = __builtin_amdgcn_mfma_f32_16x16x32_f16(AM[1], WN[0], ACC, 0, 0, 0);

__global__ __launch_bounds__(512, 2)
void lstm8p(const char* __restrict__ wsbase,
            const float* __restrict__ bx, const float* __restrict__ bh,
            const float* __restrict__ cx, float* __restrict__ out) {
    __shared__ _Float16 sm[2][2][256 * 64];   // [dbuf][A=0/W=1], 128 KiB

    const int t = threadIdx.x;
    const int wid = t >> 6;
    const int l = t & 63;
    const int wr = wid >> 2;     // 0..1
    const int wc = wid & 3;      // 0..3

    // T1: per-XCD W-column partition. xcd = bid&7 owns cb in [xcd*4, xcd*4+4);
    // within an XCD, rb varies fastest so concurrent blocks share W panels in L2.
    const int bid = blockIdx.x;
    const int c8 = bid >> 3;                  // 0..63
    const int rb = c8 & 15;                   // 16 row-blocks
    const int cb = (bid & 7) * 4 + (c8 >> 4); // 32 col-blocks, XCD-partitioned

    // ---- staging geometry: 4 A-gloads + 4 W-gloads per wave per K-tile.
    // gload g covers tile rows [g*64+wid*8, +8); lane l -> row +(l>>3),
    // 16B slot (l&7). T2 pre-swizzle on the GLOBAL side: LDS slot s receives
    // global chunk s ^ (row&7), row&7 == l>>3.
    const int lr = l >> 3;
    const int ks = ((l & 7) ^ lr) * 8;        // f16 offset within 64-k row
    unsigned offA[4], offW[4];
    #pragma unroll
    for (int g = 0; g < 4; ++g) {
        const int rowA = rb * 256 + g * 64 + wid * 8 + lr;
        offA[g] = (unsigned)rowA * 16384u + (unsigned)ks * 2u;
        const int e = g * 64 + wid * 8 + lr;
        const int gc = ((e >> 4) & 3) * H_DIM + cb * 64 + (e >> 6) * 16 + (e & 15);
        offW[g] = W2_OFF + (unsigned)gc * 16384u + (unsigned)ks * 2u;
    }
    const int ldsrow = wid * 8;

    auto STAGE_A = [&](int kt, int db) {
        const unsigned kb = (unsigned)kt * 128u;
        #pragma unroll
        for (int g = 0; g < 4; ++g)
            gload_lds16(wsbase + offA[g] + kb, (_Float16*)&sm[db][0][(g * 64 + ldsrow) * 64]);
    };
    auto STAGE_W = [&](int kt, int db) {
        const unsigned kb = (unsigned)kt * 128u;
        #pragma unroll
        for (int g = 0; g < 4; ++g)
            gload_lds16(wsbase + offW[g] + kb, (_Float16*)&sm[db][1][(g * 64 + ldsrow) * 64]);
    };

    // ---- fragment-read lane offsets (bytes within a [256][64] f16 tile).
    // row = base16 + (l&15); global 16B-chunk (tm*4 + (l>>4)) is at LDS chunk
    // ^ (row&7); row&7 == l&7 (base16 is a multiple of 16).
    int laneF[2];
    #pragma unroll
    for (int tm = 0; tm < 2; ++tm)
        laneF[tm] = (l & 15) * 128 + (((tm * 4 + (l >> 4)) ^ (l & 7)) << 4);

    auto LDA = [&](int db, int m, int tm) -> half8 {
        const char* p = (const char*)&sm[db][0][0] + (wr * 128 + m * 16) * 128 + laneF[tm];
        return *(const half8*)p;
    };
    auto LDW = [&](int db, int n, int tm) -> half8 {
        const char* p = (const char*)&sm[db][1][0] + (wc * 64 + n * 16) * 128 + laneF[tm];
        return *(const half8*)p;
    };

    f32x4 acc[8][4];
    #pragma unroll
    for (int m = 0; m < 8; ++m)
        #pragma unroll
        for (int n = 0; n < 4; ++n) acc[m][n] = (f32x4){0.f, 0.f, 0.f, 0.f};

    // ---- prologue: tiles 0,1 staged (W then A each); wait tile0 (newest 8 = tile1).
    STAGE_W(0, 0); STAGE_A(0, 0);
    STAGE_W(1, 1); STAGE_A(1, 1);
    asm volatile("s_waitcnt vmcnt(8)" ::: "memory");
    __builtin_amdgcn_s_barrier();

    // ---- one K-tile: 4 phases, 7 barriers, staging spread across p2/p3.
    auto TILE = [&](const int db, const int kt) {
        half8 a[4][2], w[4][2];
        // phase 0: read A[0-3] hi+lo, W[0-1] hi+lo; MFMA quad (0,0)
        #pragma unroll
        for (int m = 0; m < 4; ++m) { a[m][0] = LDA(db, m, 0); a[m][1] = LDA(db, m, 1); }
        #pragma unroll
        for (int n = 0; n < 2; ++n) { w[n][0] = LDW(db, n, 0); w[n][1] = LDW(db, n, 1); }
        __builtin_amdgcn_s_barrier();
        __builtin_amdgcn_s_setprio(1);
        #pragma unroll
        for (int m = 0; m < 4; ++m) { MFMA3(a[m], w[0], acc[m][0]); MFMA3(a[m], w[1], acc[m][1]); }
        __builtin_amdgcn_s_setprio(0);
        __builtin_amdgcn_s_barrier();
        // phase 1: read W[2-3]; MFMA quad (0,1). All W reads done after this phase.
        #pragma unroll
        for (int n = 2; n < 4; ++n) { w[n][0] = LDW(db, n, 0); w[n][1] = LDW(db, n, 1); }
        __builtin_amdgcn_s_barrier();
        __builtin_amdgcn_s_setprio(1);
        #pragma unroll
        for (int m = 0; m < 4; ++m) { MFMA3(a[m], w[2], acc[m][2]); MFMA3(a[m], w[3], acc[m][3]); }
        __builtin_amdgcn_s_setprio(0);
        __builtin_amdgcn_s_barrier();
        // phase 2: read A[4-7]; stage next-next W into this buffer (W reads done);
        //          MFMA quad (1,0). All A reads done after this phase.
        #pragma unroll
        for (int m = 0; m < 4; ++m) { a[m][0] = LDA(db, m + 4, 0); a[m][1] = LDA(db, m + 4, 1); }
        if (kt + 2 < NT) STAGE_W(kt + 2, db);
        __builtin_amdgcn_s_barrier();
        __builtin_amdgcn_s_setprio(1);
        #pragma unroll
        for (int m = 0; m < 4; ++m) { MFMA3(a[m], w[0], acc[m + 4][0]); MFMA3(a[m], w[1], acc[m + 4][1]); }
        __builtin_amdgcn_s_setprio(0);
        __builtin_amdgcn_s_barrier();
        // phase 3: stage next-next A (A reads done); MFMA quad (1,1);
        //          counted vmcnt at tile boundary (never 0 mid-loop).
        if (kt + 2 < NT) STAGE_A(kt + 2, db);
        __builtin_amdgcn_s_setprio(1);
        #pragma unroll
        for (int m = 0; m < 4; ++m) { MFMA3(a[m], w[2], acc[m + 4][2]); MFMA3(a[m], w[3], acc[m + 4][3]); }
        __builtin_amdgcn_s_setprio(0);
        if (kt < NT - 2) {
            asm volatile("s_waitcnt vmcnt(8)" ::: "memory");   // kt+1 landed; kt+2 in flight
            __builtin_amdgcn_s_barrier();
        } else if (kt == NT - 2) {
            asm volatile("s_waitcnt vmcnt(0)" ::: "memory");   // drain for the last tile
            __builtin_amdgcn_s_barrier();
        }
        // kt == NT-1: no further staged reads; fall through to epilogue.
    };

    for (int kt = 0; kt < NT; kt += 2) {
        TILE(0, kt);        // static dbuf indices after inlining
        TILE(1, kt + 1);
    }

    // ---- fused LSTM epilogue, fully in-register (frag n == gate n) ----
    const int hcol = cb * 64 + wc * 16 + (l & 15);
    float bs[4];
    #pragma unroll
    for (int g = 0; g < 4; ++g) bs[g] = bx[g * H_DIM + hcol] + bh[g * H_DIM + hcol];
    const int row0 = rb * 256 + wr * 128 + (l >> 4) * 4;
    #pragma unroll
    for (int m = 0; m < 8; ++m) {
        #pragma unroll
        for (int r = 0; r < 4; ++r) {
            const long base = (long)(row0 + m * 16 + r) * H_DIM + hcol;
            const float iv = fast_sigmoid(acc[m][0][r] + bs[0]);
            const float fv = fast_sigmoid(acc[m][1][r] + bs[1]);
            const float gv = fast_tanh(acc[m][2][r] + bs[2]);
            const float ov = fast_sigmoid(acc[m][3][r] + bs[3]);
            const float c0 = cx[base];
            const float cyv = fv * c0 + iv * gv;
            const float hyv = ov * fast_tanh(cyv);
            out[base] = hyv;
            out[BH_TOT + base] = cyv;
        }
    }
}

extern "C" void kernel_launch(void* const* d_in, const int* in_sizes, int n_in,
                              void* d_out, int out_size, void* d_ws, size_t ws_size,
                              hipStream_t stream) {
    (void)in_sizes; (void)n_in; (void)out_size; (void)ws_size;
    const float* x  = (const float*)d_in[0];
    const float* hx = (const float*)d_in[1];
    const float* cx = (const float*)d_in[2];
    const float* Wx = (const float*)d_in[3];
    const float* bx = (const float*)d_in[4];
    const float* Wh = (const float*)d_in[5];
    const float* bh = (const float*)d_in[6];
    float* out = (float*)d_out;

    _Float16* A2 = (_Float16*)d_ws;                     // 4096 x 8192 f16
    _Float16* W2 = (_Float16*)((char*)d_ws + W2_OFF);   // 8192 x 8192 f16

    split_all<<<2048, 256, 0, stream>>>(x, hx, Wx, Wh, A2, W2);
    lstm8p<<<512, 512, 0, stream>>>((const char*)d_ws, bx, bh, cx, out);
}